// Round 11
// baseline (824.701 us; speedup 1.0000x reference)
//
#include <hip/hip_runtime.h>
#include <hip/hip_bf16.h>
#include <math.h>

typedef __hip_bfloat16 bf16;
typedef __attribute__((ext_vector_type(8))) short short8;   // 8 bf16 = 4 VGPRs
typedef __attribute__((ext_vector_type(4))) float f32x4;

#define DEV __device__ __forceinline__

// problem constants
constexpr int CB = 8, CN = 1024, CD = 768, CH = 12, CK = 64, CF = 3072;
constexpr int ROWS = CB * CN;  // 8192

// ---------------------------------------------------------------- utilities
DEV void gload_lds16(const void* g, void* l) {
  __builtin_amdgcn_global_load_lds(
      (const __attribute__((address_space(1))) void*)g,
      (__attribute__((address_space(3))) void*)l, 16, 0, 0);
}

// ------------------------------------------------------- weight prep (T + cast)
__global__ __launch_bounds__(256) void transpose_f32_bf16(
    const float* __restrict__ in, bf16* __restrict__ out, int R, int C,
    float scale) {
  __shared__ float tile[32][33];
  const int tx = threadIdx.x & 31, ty = threadIdx.x >> 5;  // 32 x 8
  const int c0 = blockIdx.x * 32, r0 = blockIdx.y * 32;
#pragma unroll
  for (int i = 0; i < 4; ++i)
    tile[ty + i * 8][tx] = in[(size_t)(r0 + ty + i * 8) * C + c0 + tx];
  __syncthreads();
#pragma unroll
  for (int i = 0; i < 4; ++i)
    out[(size_t)(c0 + ty + i * 8) * R + r0 + tx] =
        __float2bfloat16(tile[tx][ty + i * 8] * scale);
}

// ---------------------------------------------------------------- LayerNorm
__global__ __launch_bounds__(256) void ln_bf16(
    const float* __restrict__ in, const float* __restrict__ gamma,
    const float* __restrict__ beta, bf16* __restrict__ out) {
  const int row = blockIdx.x;
  const int tid = threadIdx.x;
  const float* x = in + (size_t)row * CD;
  const float v0 = x[tid], v1 = x[tid + 256], v2 = x[tid + 512];
  float s = v0 + v1 + v2;
  float q = v0 * v0 + v1 * v1 + v2 * v2;
#pragma unroll
  for (int off = 32; off > 0; off >>= 1) {
    s += __shfl_xor(s, off);
    q += __shfl_xor(q, off);
  }
  __shared__ float sm[8];
  const int w = tid >> 6, l = tid & 63;
  if (l == 0) { sm[w] = s; sm[4 + w] = q; }
  __syncthreads();
  s = sm[0] + sm[1] + sm[2] + sm[3];
  q = sm[4] + sm[5] + sm[6] + sm[7];
  const float mean = s * (1.f / CD);
  const float var = q * (1.f / CD) - mean * mean;
  const float rs = rsqrtf(var + 1e-5f);
  bf16* o = out + (size_t)row * CD;
  o[tid]       = __float2bfloat16((v0 - mean) * rs * gamma[tid]       + beta[tid]);
  o[tid + 256] = __float2bfloat16((v1 - mean) * rs * gamma[tid + 256] + beta[tid + 256]);
  o[tid + 512] = __float2bfloat16((v2 - mean) * rs * gamma[tid + 512] + beta[tid + 512]);
}

// ------------------------------------------- 256x256 GEMM, 2 phases/K-tile
// R11: barrier count halved (4/K-tile, was 8) — 32 MFMA per barrier-pair.
// All staging addresses hoisted to persistent pointers (advance +64/tile);
// ds_read bases precomputed per lane (swizzle folded) -> base + imm offset.
// Stage slots: ph0 -> A(t+1) [buf^1], ph1 -> B(t+2) [buf; B(t) dead after
// ph0's closing barrier]. vmcnt(4) at ph1 end: outstanding = B(t+1)4 oldest,
// A(t+1)4, B(t+2)4 -> waits tile t+1 landed, leaves B(t+2) in flight.
// t==NT-2: vmcnt(0). Prologue: A(0),B(0),B(1) + vmcnt(4).
// T2 swizzle: inverse-swizzled GLOBAL source + swizzled ds_read (rule #21).
template <int EPI>
__global__ __launch_bounds__(512, 2) void gemm256_kernel(
    const bf16* __restrict__ A, const bf16* __restrict__ Bt, int Kd, int nbx,
    bf16* __restrict__ dst0, bf16* __restrict__ dst1, bf16* __restrict__ dst2,
    const float* __restrict__ bias0, const float* __restrict__ bias1,
    const float* __restrict__ bias2) {
  __shared__ __align__(16) bf16 As[2][256 * 64];  // 64 KB
  __shared__ __align__(16) bf16 Bs[2][256 * 64];  // 64 KB

  const int tid = threadIdx.x;
  const int w = tid >> 6, l = tid & 63;
  const int wr = w >> 2, wc = w & 3;  // 2 x 4 wave grid
  const int l15 = l & 15, lg = l >> 4;

  const int L = blockIdx.x;
  const int cpx = gridDim.x >> 3;
  const int g = (L & 7) * cpx + (L >> 3);   // XCD swizzle (grid % 8 == 0)
  const int by = g / nbx, bx = g - by * nbx;
  const int rowBase = by * 256, colBase = bx * 256;
  const bool vswap = (EPI == 0) && (colBase >= 2 * CD);
  const int NT = Kd >> 6;

  // ---- hoisted staging pointers: slot s = i*512+tid; row=s>>3, c16=s&7,
  // gc16 = c16 ^ (row&7) (inverse swizzle on global source).
  const bf16* pA[4];
  const bf16* pB[4];
  void* ldsA[4][2];
  void* ldsB[4][2];
#pragma unroll
  for (int i = 0; i < 4; ++i) {
    const int s = i * 512 + tid;
    const int row = s >> 3, c16 = s & 7;
    const int gc16 = c16 ^ (row & 7);
    pA[i] = A + (size_t)(rowBase + row) * Kd + gc16 * 8;         // k=0
    pB[i] = Bt + (size_t)(colBase + row) * Kd + gc16 * 8;        // k=0
#pragma unroll
    for (int par = 0; par < 2; ++par) {
      ldsA[i][par] = (void*)&As[par][(i * 512 + w * 64) * 8];
      ldsB[i][par] = (void*)&Bs[par][(i * 512 + w * 64) * 8];
    }
  }
  auto stageA = [&](int parity) {
#pragma unroll
    for (int i = 0; i < 4; ++i) { gload_lds16(pA[i], ldsA[i][parity]); pA[i] += 64; }
  };
  auto stageB = [&](int parity) {
#pragma unroll
    for (int i = 0; i < 4; ++i) { gload_lds16(pB[i], ldsB[i][parity]); pB[i] += 64; }
  };

  // ---- hoisted ds_read bases: A row = wr*128 + m*16 + l15, swizzle key l15&7
  const int c16k0 = (0 * 4 + lg) ^ (l15 & 7);
  const int c16k1 = (1 * 4 + lg) ^ (l15 & 7);
  const bf16* aBase[2][2];  // [buf][kh]
  const bf16* bBase[2][2];
#pragma unroll
  for (int buf = 0; buf < 2; ++buf) {
    aBase[buf][0] = &As[buf][(wr * 128 + l15) * 64 + c16k0 * 8];
    aBase[buf][1] = &As[buf][(wr * 128 + l15) * 64 + c16k1 * 8];
    bBase[buf][0] = &Bs[buf][(wc * 64 + l15) * 64 + c16k0 * 8];
    bBase[buf][1] = &Bs[buf][(wc * 64 + l15) * 64 + c16k1 * 8];
  }

  f32x4 acc[8][4];
#pragma unroll
  for (int m = 0; m < 8; ++m)
#pragma unroll
    for (int n = 0; n < 4; ++n)
#pragma unroll
      for (int r = 0; r < 4; ++r) acc[m][n][r] = 0.f;

  // prologue: A(0), B(0), B(1); wait A0+B0 (oldest 8), leave B1 in flight
  stageA(0);
  stageB(0);
  stageB(1);
  asm volatile("s_waitcnt vmcnt(4)" ::: "memory");
  __builtin_amdgcn_s_barrier();

  for (int t = 0; t < NT; ++t) {
    const int buf = t & 1;
    short8 bfrag[4][2], afr[4][2];
    // ================= phase 0: m 0..3 =================
#pragma unroll
    for (int n = 0; n < 4; ++n)
#pragma unroll
      for (int kh = 0; kh < 2; ++kh)
        bfrag[n][kh] = *reinterpret_cast<const short8*>(bBase[buf][kh] + n * 1024);
#pragma unroll
    for (int m = 0; m < 4; ++m)
#pragma unroll
      for (int kh = 0; kh < 2; ++kh)
        afr[m][kh] = *reinterpret_cast<const short8*>(aBase[buf][kh] + m * 1024);
    if (t + 1 < NT) stageA((t + 1) & 1);
    __builtin_amdgcn_s_barrier();
    __builtin_amdgcn_s_setprio(1);
    if (!vswap) {
#pragma unroll
      for (int kh = 0; kh < 2; ++kh)
#pragma unroll
        for (int m = 0; m < 4; ++m)
#pragma unroll
          for (int n = 0; n < 4; ++n)
            acc[m][n] = __builtin_amdgcn_mfma_f32_16x16x32_bf16(
                afr[m][kh], bfrag[n][kh], acc[m][n], 0, 0, 0);
    } else {
#pragma unroll
      for (int kh = 0; kh < 2; ++kh)
#pragma unroll
        for (int m = 0; m < 4; ++m)
#pragma unroll
          for (int n = 0; n < 4; ++n)
            acc[m][n] = __builtin_amdgcn_mfma_f32_16x16x32_bf16(
                bfrag[n][kh], afr[m][kh], acc[m][n], 0, 0, 0);
    }
    __builtin_amdgcn_s_setprio(0);
    __builtin_amdgcn_s_barrier();
    // ================= phase 1: m 4..7 =================
#pragma unroll
    for (int m = 0; m < 4; ++m)
#pragma unroll
      for (int kh = 0; kh < 2; ++kh)
        afr[m][kh] = *reinterpret_cast<const short8*>(aBase[buf][kh] + (m + 4) * 1024);
    if (t + 2 < NT) stageB(t & 1);  // B(t+2) -> buf (B(t) dead since ph0 barrier)
    __builtin_amdgcn_s_barrier();
    __builtin_amdgcn_s_setprio(1);
    if (!vswap) {
#pragma unroll
      for (int kh = 0; kh < 2; ++kh)
#pragma unroll
        for (int m = 0; m < 4; ++m)
#pragma unroll
          for (int n = 0; n < 4; ++n)
            acc[m + 4][n] = __builtin_amdgcn_mfma_f32_16x16x32_bf16(
                afr[m][kh], bfrag[n][kh], acc[m + 4][n], 0, 0, 0);
    } else {
#pragma unroll
      for (int kh = 0; kh < 2; ++kh)
#pragma unroll
        for (int m = 0; m < 4; ++m)
#pragma unroll
          for (int n = 0; n < 4; ++n)
            acc[m + 4][n] = __builtin_amdgcn_mfma_f32_16x16x32_bf16(
                bfrag[n][kh], afr[m][kh], acc[m + 4][n], 0, 0, 0);
    }
    __builtin_amdgcn_s_setprio(0);
    if (t < NT - 2)       asm volatile("s_waitcnt vmcnt(4)" ::: "memory");
    else if (t == NT - 2) asm volatile("s_waitcnt vmcnt(0)" ::: "memory");
    __builtin_amdgcn_s_barrier();
  }

  if constexpr (EPI == 0) {
    if (vswap) {
#pragma unroll
      for (int m = 0; m < 8; ++m) {
        const int nrow = rowBase + wr * 128 + m * 16 + l15;
        const int b = nrow >> 10, nn = nrow & 1023;
#pragma unroll
        for (int n = 0; n < 4; ++n) {
#pragma unroll
          for (int fr = 0; fr < 4; ++fr) {
            const int hk = (colBase - 2 * CD) + wc * 64 + n * 16 + lg * 4 + fr;
            const float v = acc[m][n][fr] + bias2[hk];
            const int h = hk >> 6, kk = hk & 63;
            dst2[((size_t)(b * CH + h) * CK + kk) * CN + nn] = __float2bfloat16(v);
          }
        }
      }
    } else {
      const int which = colBase / CD;  // 0=Q, 1=K
#pragma unroll
      for (int m = 0; m < 8; ++m) {
#pragma unroll
        for (int n = 0; n < 4; ++n) {
          const int col = colBase + wc * 64 + n * 16 + l15;
          const int hk = col - which * CD;
          const float bias = (which == 0) ? bias0[hk] * 0.125f : bias1[hk];
          bf16* dst = (which == 0) ? dst0 : dst1;
          const int h = hk >> 6, kk = hk & 63;
#pragma unroll
          for (int fr = 0; fr < 4; ++fr) {
            const int row = rowBase + wr * 128 + m * 16 + lg * 4 + fr;
            const int b = row >> 10, nn = row & 1023;
            dst[(((size_t)(b * CH + h)) * CN + nn) * CK + kk] =
                __float2bfloat16(acc[m][n][fr] + bias);
          }
        }
      }
    }
  } else {  // EPI == 2: +bias, exact GELU -> bf16 [*, CF]
#pragma unroll
    for (int m = 0; m < 8; ++m) {
#pragma unroll
      for (int n = 0; n < 4; ++n) {
        const int col = colBase + wc * 64 + n * 16 + l15;
        const float bias = bias0[col];
#pragma unroll
        for (int fr = 0; fr < 4; ++fr) {
          const int row = rowBase + wr * 128 + m * 16 + lg * 4 + fr;
          const float v = acc[m][n][fr] + bias;
          const float gel = 0.5f * v * (1.0f + erff(v * 0.70710678118654752f));
          dst0[(size_t)row * CF + col] = __float2bfloat16(gel);
        }
      }
    }
  }
}

// ---------------------------------------------------------------- GEMM 128²
// (m97 structure, for the narrow N=768 GEMMs). EPI 1: +bias +resid, fp32 out.
template <int EPI>
__global__ __launch_bounds__(256) void gemm_bf16_kernel(
    const bf16* __restrict__ A, const bf16* __restrict__ Bt, int Kd, int nbx,
    float* __restrict__ outF, const float* __restrict__ bias0,
    const float* __restrict__ resid) {
  __shared__ __align__(16) bf16 As[128 * 32];
  __shared__ __align__(16) bf16 Bs[128 * 32];
  const int tid = threadIdx.x;
  const int w = tid >> 6, l = tid & 63;
  const int wr = w >> 1, wc = w & 1;
  const int l15 = l & 15, lg = l >> 4;
  const int L = blockIdx.x;
  const int cpx = gridDim.x >> 3;
  const int g = (L & 7) * cpx + (L >> 3);
  const int by = g / nbx, bx = g - by * nbx;
  const int rowBase = by * 128;
  const int colBase = bx * 128;

  f32x4 acc[4][4];
#pragma unroll
  for (int i = 0; i < 4; ++i)
#pragma unroll
    for (int j = 0; j < 4; ++j)
#pragma unroll
      for (int r = 0; r < 4; ++r) acc[i][j][r] = 0.f;

  for (int k0 = 0; k0 < Kd; k0 += 32) {
    __syncthreads();
#pragma unroll
    for (int i = 0; i < 2; ++i) {
      const int c = w * 128 + i * 64 + l;
      const int r = c >> 2, cc = c & 3;
      gload_lds16(A + (size_t)(rowBase + r) * Kd + k0 + cc * 8,
                  (void*)&As[(w * 128 + i * 64) * 8]);
      gload_lds16(Bt + (size_t)(colBase + r) * Kd + k0 + cc * 8,
                  (void*)&Bs[(w * 128 + i * 64) * 8]);
    }
    __syncthreads();
    short8 af[4], bfr[4];
#pragma unroll
    for (int fm = 0; fm < 4; ++fm)
      af[fm] = *reinterpret_cast<const short8*>(
          &As[(wr * 64 + fm * 16 + l15) * 32 + lg * 8]);
#pragma unroll
    for (int fn = 0; fn < 4; ++fn)
      bfr[fn] = *reinterpret_cast<const short8*>(
          &Bs[(wc * 64 + fn * 16 + l15) * 32 + lg * 8]);
#pragma unroll
    for (int fm = 0; fm < 4; ++fm)
#pragma unroll
      for (int fn = 0; fn < 4; ++fn)
        acc[fm][fn] = __builtin_amdgcn_mfma_f32_16x16x32_bf16(
            af[fm], bfr[fn], acc[fm][fn], 0, 0, 0);
  }

  const int mrow0 = rowBase + wr * 64;
  const int ncol0 = colBase + wc * 64;
#pragma unroll
  for (int fm = 0; fm < 4; ++fm) {
#pragma unroll
    for (int fn = 0; fn < 4; ++fn) {
      const int col = ncol0 + fn * 16 + l15;
#pragma unroll
      for (int fr = 0; fr < 4; ++fr) {
        const int row = mrow0 + fm * 16 + lg * 4 + fr;
        float v = acc[fm][fn][fr];
        v += bias0[col] + resid[(size_t)row * CD + col];
        outF[(size_t)row * CD + col] = v;
      }
    }
  }
}

// ---------------------------------------------------------------- attention
// R9 proven: block-staged flash attention. grid 1536, head XCD-affinity
// (bh=(i&7)+8*(i>>7), qb=(i>>3)&15). 4 waves x 16 q-rows share K/V tiles
// staged via global_load_lds + T2 swizzle; double-buffered; swapped QK^T,
// defer-max, per-lane lsum. Q pre-scaled 1/8.
__global__ __launch_bounds__(256) void attn_kernel(
    const bf16* __restrict__ Qb, const bf16* __restrict__ Kb,
    const bf16* __restrict__ Vtb, bf16* __restrict__ ctxb) {
  __shared__ __align__(16) bf16 Ks[2][64 * 64];  // [m][k-dim], 8 KB/buf
  __shared__ __align__(16) bf16 Vs[2][64 * 64];  // Vt tile [d][key], 8 KB/buf
  __shared__ __align__(16) bf16 Ps[4][16][72];   // per-wave P tile

  const int tid = threadIdx.x;
  const int w = tid >> 6, l = tid & 63;
  const int l15 = l & 15, lg = l >> 4;
  const int i = blockIdx.x;
  const int bh = (i & 7) + 8 * (i >> 7);  // head 0..95, fixed per XCD
  const int qb = (i >> 3) & 15;           // 64-row q block
  const int b = bh / CH, h = bh - b * CH;
  const bf16* Qh  = Qb  + (size_t)bh * CN * CK;
  const bf16* Kh  = Kb  + (size_t)bh * CN * CK;
  const bf16* Vth = Vtb + (size_t)bh * CK * CN;
  const int q0 = qb * 64 + w * 16;

  auto stageKV = [&](int kt, int buf) {
#pragma unroll
    for (int ii = 0; ii < 2; ++ii) {
      const int s = ii * 256 + w * 64 + l;
      const int row = s >> 3, c16 = s & 7;
      const int gc16 = c16 ^ (row & 7);
      gload_lds16(Kh + (size_t)(kt * 64 + row) * CK + gc16 * 8,
                  (void*)&Ks[buf][(ii * 256 + w * 64) * 8]);
      gload_lds16(Vth + (size_t)row * CN + kt * 64 + gc16 * 8,
                  (void*)&Vs[buf][(ii * 256 + w * 64) * 8]);
    }
  };
  auto read_k = [&](int buf, int mb, int c) -> short8 {
    const int row = mb * 16 + l15;
    const int c16 = (c * 4 + lg) ^ (l15 & 7);
    return *reinterpret_cast<const short8*>(&Ks[buf][row * 64 + c16 * 8]);
  };
  auto read_v = [&](int buf, int kb, int c) -> short8 {
    const int row = kb * 16 + l15;
    const int c16 = (c * 4 + lg) ^ (l15 & 7);
    return *reinterpret_cast<const short8*>(&Vs[buf][row * 64 + c16 * 8]);
  };

  short8 aq[2];
#pragma unroll
  for (int c = 0; c < 2; ++c)
    aq[c] = *reinterpret_cast<const short8*>(
        Qh + (size_t)(q0 + l15) * CK + c * 32 + lg * 8);

  f32x4 oacc[4];
  float mreg = -INFINITY, lpart = 0.f;
#pragma unroll
  for (int kb = 0; kb < 4; ++kb)
#pragma unroll
    for (int r = 0; r < 4; ++r) oacc[kb][r] = 0.f;

  stageKV(0, 0);
  asm volatile("s_waitcnt vmcnt(0)" ::: "memory");
  __builtin_amdgcn_s_barrier();

#pragma unroll 1
  for (int kt = 0; kt < 16; ++kt) {
    const int buf = kt & 1;
    if (kt < 15) stageKV(kt + 1, buf ^ 1);

    short8 kf[4][2];
#pragma unroll
    for (int mb = 0; mb < 4; ++mb)
#pragma unroll
      for (int c = 0; c < 2; ++c) kf[mb][c] = read_k(buf, mb, c);

    f32x4 sacc[4];
    __builtin_amdgcn_s_setprio(1);
#pragma unroll
    for (int mb = 0; mb < 4; ++mb) {
      f32x4 z;
#pragma unroll
      for (int r = 0; r < 4; ++r) z[r] = 0.f;
      z = __builtin_amdgcn_mfma_f32_16x16x32_bf16(kf[mb][0], aq[0], z, 0, 0, 0);
      z = __builtin_amdgcn_mfma_f32_16x16x32_bf16(kf[mb][1], aq[1], z, 0, 0, 0);
      sacc[mb] = z;
    }
    __builtin_amdgcn_s_setprio(0);

    float mx = sacc[0][0];
#pragma unroll
    for (int mb = 0; mb < 4; ++mb)
#pragma unroll
      for (int r = 0; r < 4; ++r) mx = fmaxf(mx, sacc[mb][r]);
    mx = fmaxf(mx, __shfl_xor(mx, 16));
    mx = fmaxf(mx, __shfl_xor(mx, 32));
    if (!__all(mx - mreg <= 8.f)) {
      const float mn = fmaxf(mreg, mx);
      const float alpha = __expf(mreg - mn);
      float alr[4];
#pragma unroll
      for (int r = 0; r < 4; ++r) alr[r] = __shfl(alpha, lg * 4 + r);
#pragma unroll
      for (int kb = 0; kb < 4; ++kb)
#pragma unroll
        for (int r = 0; r < 4; ++r) oacc[kb][r] *= alr[r];
      lpart *= alpha;
      mreg = mn;
    }
#pragma unroll
    for (int mb = 0; mb < 4; ++mb)
#pragma unroll
      for (int r = 0; r < 4; ++r) {
        const float p = __expf(sacc[mb][r] - mreg);
        sacc[mb][r] = p;
        lpart += p;
      }

    short8 vf[4][2];
#pragma unroll
    for (int kb = 0; kb < 4; ++kb)
#pragma unroll
      for (int c = 0; c < 2; ++c) vf[kb][c] = read_v(buf, kb, c);

#pragma unroll
    for (int mb = 0; mb < 4; ++mb) {
      bf16 tmp[4];
#pragma unroll
      for (int r = 0; r < 4; ++r) tmp[r] = __float2bfloat16(sacc[mb][r]);
      *reinterpret_cast<uint2*>(&Ps[w][l15][mb * 16 + lg * 4]) =
          *reinterpret_cast<const uint2*>(tmp);
    }
    const short8 pa0 = *reinterpret_cast<const short8*>(&Ps[w][l15][lg * 8]);
    const short8 pa1 = *reinterpret_cast<const short8*>(&Ps[w][l15][32 + lg * 8]);

    __builtin_amdgcn_s_setprio(1);
#pragma unroll
    for (int kb = 0; kb < 4; ++kb) {
      oacc[kb] = __builtin_amdgcn_mfma_f32_16x16x32_bf16(pa0, vf[kb][0],
                                                         oacc[kb], 0, 0, 0);
      oacc[kb] = __builtin_amdgcn_mfma_f32_16x16x32_bf16(pa1, vf[kb][1],
                                                         oacc[kb], 0, 0, 0);
    }
    __builtin_amdgcn_s_setprio(0);

    asm volatile("s_waitcnt vmcnt(0)" ::: "memory");
    __builtin_amdgcn_s_barrier();
  }

  float lsum = lpart;
  lsum += __shfl_xor(lsum, 16);
  lsum += __shfl_xor(lsum, 32);

#pragma unroll
  for (int r = 0; r < 4; ++r) {
    const float inv = 1.f / __shfl(lsum, lg * 4 + r);
    const int n = q0 + lg * 4 + r;
    bf16* dst = ctxb + ((size_t)(b * CN + n)) * CD + h * CK;
#pragma unroll
    for (int kb = 0; kb < 4; ++kb)
      dst[kb * 16 + l15] = __float2bfloat16(oacc[kb][r] * inv);
  }
}

// ---------------------------------------------------------------- launcher
extern "C" void kernel_launch(void* const* d_in, const int* in_sizes, int n_in,
                              void* d_out, int out_size, void* d_ws,
                              size_t ws_size, hipStream_t stream) {
  const float* x    = (const float*)d_in[0];
  const float* ln1g = (const float*)d_in[1];
  const float* ln1b = (const float*)d_in[2];
  const float* wq   = (const float*)d_in[3];
  const float* bq   = (const float*)d_in[4];
  const float* wk   = (const float*)d_in[5];
  const float* bk   = (const float*)d_in[6];
  const float* wv   = (const float*)d_in[7];
  const float* bv   = (const float*)d_in[8];
  const float* wo   = (const float*)d_in[9];
  const float* bo   = (const float*)d_in[10];
  const float* ln2g = (const float*)d_in[11];
  const float* ln2b = (const float*)d_in[12];
  const float* w1   = (const float*)d_in[13];
  const float* b1   = (const float*)d_in[14];
  const float* w2   = (const float*)d_in[15];
  const float* b2   = (const float*)d_in[16];

  char* ws = (char*)d_ws;
  bf16* wqkvt = (bf16*)(ws + 0);
  bf16* wot   = (bf16*)(ws + 3538944);
  bf16* w1t   = (bf16*)(ws + 4718592);
  bf16* w2t   = (bf16*)(ws + 9437184);
  bf16* h1    = (bf16*)(ws + 14155776);
  bf16* Qbuf  = (bf16*)(ws + 26738688);
  bf16* Kbuf  = (bf16*)(ws + 39321600);
  bf16* Vtbuf = (bf16*)(ws + 51904512);
  bf16* gb    = (bf16*)(ws + 14155776);  // reuse h1+Q+K+V region
  bf16* ctxb  = (bf16*)(ws + 64487424);
  bf16* h2    = (bf16*)(ws + 64487424);  // reuse ctx region
  float* outb = (float*)(ws + 77070336);
  float* y    = (float*)d_out;

  transpose_f32_bf16<<<dim3(24, 24), 256, 0, stream>>>(wq, wqkvt, 768, 768, 0.125f);
  transpose_f32_bf16<<<dim3(24, 24), 256, 0, stream>>>(wk, wqkvt + 768 * 768, 768, 768, 1.f);
  transpose_f32_bf16<<<dim3(24, 24), 256, 0, stream>>>(wv, wqkvt + 2 * 768 * 768, 768, 768, 1.f);
  transpose_f32_bf16<<<dim3(24, 24), 256, 0, stream>>>(wo, wot, 768, 768, 1.f);
  transpose_f32_bf16<<<dim3(96, 24), 256, 0, stream>>>(w1, w1t, 768, 3072, 1.f);
  transpose_f32_bf16<<<dim3(24, 96), 256, 0, stream>>>(w2, w2t, 3072, 768, 1.f);

  ln_bf16<<<ROWS, 256, 0, stream>>>(x, ln1g, ln1b, h1);

  // QKV: 256² 2-phase, grid 32x9 = 288 (%8==0)
  gemm256_kernel<0><<<(ROWS / 256) * 9, 512, 0, stream>>>(
      h1, wqkvt, 768, 9, Qbuf, Kbuf, Vtbuf, bq, bk, bv);

  attn_kernel<<<CB * CH * 16, 256, 0, stream>>>(Qbuf, Kbuf, Vtbuf, ctxb);

  gemm_bf16_kernel<1><<<6 * (ROWS / 128), 256, 0, stream>>>(
      ctxb, wot, 768, 6, outb, bo, x);

  ln_bf16<<<ROWS, 256, 0, stream>>>(outb, ln2g, ln2b, h2);

  // MLP1: 256² 2-phase, grid 32x12 = 384 (%8==0)
  gemm256_kernel<2><<<(ROWS / 256) * 12, 512, 0, stream>>>(
      h2, w1t, 768, 12, gb, nullptr, nullptr, b1, nullptr, nullptr);

  gemm_bf16_kernel<1><<<6 * (ROWS / 128), 256, 0, stream>>>(
      gb, w2t, 3072, 6, y, b2, outb);

  (void)in_sizes; (void)n_in; (void)out_size; (void)ws_size;
}

// Round 12
// 475.638 us; speedup vs baseline: 1.7339x; 1.7339x over previous
//
#include <hip/hip_runtime.h>
#include <hip/hip_bf16.h>
#include <math.h>
#include <type_traits>

typedef __hip_bfloat16 bf16;
typedef __attribute__((ext_vector_type(8))) short short8;   // 8 bf16 = 4 VGPRs
typedef __attribute__((ext_vector_type(4))) float f32x4;

#define DEV __device__ __forceinline__

// problem constants
constexpr int CB = 8, CN = 1024, CD = 768, CH = 12, CK = 64, CF = 3072;
constexpr int ROWS = CB * CN;  // 8192

// ---------------------------------------------------------------- utilities
DEV void gload_lds16(const void* g, void* l) {
  __builtin_amdgcn_global_load_lds(
      (const __attribute__((address_space(1))) void*)g,
      (__attribute__((address_space(3))) void*)l, 16, 0, 0);
}

// ------------------------------------------------------- weight prep (T + cast)
__global__ __launch_bounds__(256) void transpose_f32_bf16(
    const float* __restrict__ in, bf16* __restrict__ out, int R, int C,
    float scale) {
  __shared__ float tile[32][33];
  const int tx = threadIdx.x & 31, ty = threadIdx.x >> 5;  // 32 x 8
  const int c0 = blockIdx.x * 32, r0 = blockIdx.y * 32;
#pragma unroll
  for (int i = 0; i < 4; ++i)
    tile[ty + i * 8][tx] = in[(size_t)(r0 + ty + i * 8) * C + c0 + tx];
  __syncthreads();
#pragma unroll
  for (int i = 0; i < 4; ++i)
    out[(size_t)(c0 + ty + i * 8) * R + r0 + tx] =
        __float2bfloat16(tile[tx][ty + i * 8] * scale);
}

// ---------------------------------------------------------------- LayerNorm
__global__ __launch_bounds__(256) void ln_bf16(
    const float* __restrict__ in, const float* __restrict__ gamma,
    const float* __restrict__ beta, bf16* __restrict__ out) {
  const int row = blockIdx.x;
  const int tid = threadIdx.x;
  const float* x = in + (size_t)row * CD;
  const float v0 = x[tid], v1 = x[tid + 256], v2 = x[tid + 512];
  float s = v0 + v1 + v2;
  float q = v0 * v0 + v1 * v1 + v2 * v2;
#pragma unroll
  for (int off = 32; off > 0; off >>= 1) {
    s += __shfl_xor(s, off);
    q += __shfl_xor(q, off);
  }
  __shared__ float sm[8];
  const int w = tid >> 6, l = tid & 63;
  if (l == 0) { sm[w] = s; sm[4 + w] = q; }
  __syncthreads();
  s = sm[0] + sm[1] + sm[2] + sm[3];
  q = sm[4] + sm[5] + sm[6] + sm[7];
  const float mean = s * (1.f / CD);
  const float var = q * (1.f / CD) - mean * mean;
  const float rs = rsqrtf(var + 1e-5f);
  bf16* o = out + (size_t)row * CD;
  o[tid]       = __float2bfloat16((v0 - mean) * rs * gamma[tid]       + beta[tid]);
  o[tid + 256] = __float2bfloat16((v1 - mean) * rs * gamma[tid + 256] + beta[tid + 256]);
  o[tid + 512] = __float2bfloat16((v2 - mean) * rs * gamma[tid + 512] + beta[tid + 512]);
}

// ------------------------------------------- 256x256 GEMM, 2 phases/K-tile
// R12 = R11's schedule with rule-#20 fixed: K-loop unrolled by 2 so the
// buffer index is COMPILE-TIME (integral_constant) — no runtime-indexed
// pointer arrays, no scratch. 4 barriers/K-tile, 32 MFMA per barrier-pair.
// Stage slots: ph0 -> A(t+1)[buf^1], ph1 -> B(t+2)[buf] (B(t) dead after
// ph0's closing barrier). vmcnt(4) at ph1 end: outstanding = B(t+1)x4
// oldest, A(t+1)x4, B(t+2)x4 -> tile t+1 landed, B(t+2) in flight.
// t==NT-2: vmcnt(0). Prologue: A(0),B(0),B(1)+vmcnt(4). NT always even.
// T2 swizzle: inverse-swizzled GLOBAL source + swizzled ds_read (rule #21).
template <int EPI>
__global__ __launch_bounds__(512, 2) void gemm256_kernel(
    const bf16* __restrict__ A, const bf16* __restrict__ Bt, int Kd, int nbx,
    bf16* __restrict__ dst0, bf16* __restrict__ dst1, bf16* __restrict__ dst2,
    const float* __restrict__ bias0, const float* __restrict__ bias1,
    const float* __restrict__ bias2) {
  __shared__ __align__(16) bf16 As[2][256 * 64];  // 64 KB
  __shared__ __align__(16) bf16 Bs[2][256 * 64];  // 64 KB

  const int tid = threadIdx.x;
  const int w = tid >> 6, l = tid & 63;
  const int wr = w >> 2, wc = w & 3;  // 2 x 4 wave grid
  const int l15 = l & 15, lg = l >> 4;

  const int L = blockIdx.x;
  const int cpx = gridDim.x >> 3;
  const int g = (L & 7) * cpx + (L >> 3);   // XCD swizzle (grid % 8 == 0)
  const int by = g / nbx, bx = g - by * nbx;
  const int rowBase = by * 256, colBase = bx * 256;
  const bool vswap = (EPI == 0) && (colBase >= 2 * CD);
  const int NT = Kd >> 6;  // 12 or 48 — always even

  // persistent staging pointers (static indices only): slot s = i*512+tid
  const bf16* pA[4];
  const bf16* pB[4];
  int ldsOff[4];  // element offset of this thread's stage slot within a buffer
#pragma unroll
  for (int i = 0; i < 4; ++i) {
    const int s = i * 512 + tid;
    const int row = s >> 3, c16 = s & 7;
    const int gc16 = c16 ^ (row & 7);      // inverse swizzle on source
    pA[i] = A + (size_t)(rowBase + row) * Kd + gc16 * 8;
    pB[i] = Bt + (size_t)(colBase + row) * Kd + gc16 * 8;
    ldsOff[i] = (i * 512 + w * 64) * 8;
  }

  f32x4 acc[8][4];
#pragma unroll
  for (int m = 0; m < 8; ++m)
#pragma unroll
    for (int n = 0; n < 4; ++n)
#pragma unroll
      for (int r = 0; r < 4; ++r) acc[m][n][r] = 0.f;

  // swizzled read column keys (compile-time kh)
  const int c16k0 = lg ^ (l15 & 7);
  const int c16k1 = (4 + lg) ^ (l15 & 7);

  // ---------------- tile body, BUF known at compile time ----------------
  auto tile_body = [&](int t, auto bufc) {
    constexpr int BUF = decltype(bufc)::value;
    short8 bfrag[4][2], afr[4][2];
    // ========== phase 0: m 0..3 ==========
#pragma unroll
    for (int n = 0; n < 4; ++n) {
      const int row = wc * 64 + n * 16 + l15;
      bfrag[n][0] = *reinterpret_cast<const short8*>(&Bs[BUF][row * 64 + c16k0 * 8]);
      bfrag[n][1] = *reinterpret_cast<const short8*>(&Bs[BUF][row * 64 + c16k1 * 8]);
    }
#pragma unroll
    for (int m = 0; m < 4; ++m) {
      const int row = wr * 128 + m * 16 + l15;
      afr[m][0] = *reinterpret_cast<const short8*>(&As[BUF][row * 64 + c16k0 * 8]);
      afr[m][1] = *reinterpret_cast<const short8*>(&As[BUF][row * 64 + c16k1 * 8]);
    }
    if (t + 1 < NT) {  // stage A(t+1) -> other buffer
#pragma unroll
      for (int i = 0; i < 4; ++i) {
        gload_lds16(pA[i], (void*)&As[BUF ^ 1][ldsOff[i]]);
        pA[i] += 64;
      }
    }
    __builtin_amdgcn_s_barrier();
    __builtin_amdgcn_s_setprio(1);
    if (!vswap) {
#pragma unroll
      for (int kh = 0; kh < 2; ++kh)
#pragma unroll
        for (int m = 0; m < 4; ++m)
#pragma unroll
          for (int n = 0; n < 4; ++n)
            acc[m][n] = __builtin_amdgcn_mfma_f32_16x16x32_bf16(
                afr[m][kh], bfrag[n][kh], acc[m][n], 0, 0, 0);
    } else {
#pragma unroll
      for (int kh = 0; kh < 2; ++kh)
#pragma unroll
        for (int m = 0; m < 4; ++m)
#pragma unroll
          for (int n = 0; n < 4; ++n)
            acc[m][n] = __builtin_amdgcn_mfma_f32_16x16x32_bf16(
                bfrag[n][kh], afr[m][kh], acc[m][n], 0, 0, 0);
    }
    __builtin_amdgcn_s_setprio(0);
    __builtin_amdgcn_s_barrier();
    // ========== phase 1: m 4..7 ==========
#pragma unroll
    for (int m = 0; m < 4; ++m) {
      const int row = wr * 128 + (m + 4) * 16 + l15;
      afr[m][0] = *reinterpret_cast<const short8*>(&As[BUF][row * 64 + c16k0 * 8]);
      afr[m][1] = *reinterpret_cast<const short8*>(&As[BUF][row * 64 + c16k1 * 8]);
    }
    if (t + 2 < NT) {  // stage B(t+2) -> same buffer (B(t) dead since ph0)
#pragma unroll
      for (int i = 0; i < 4; ++i) {
        gload_lds16(pB[i], (void*)&Bs[BUF][ldsOff[i]]);
        pB[i] += 64;
      }
    }
    __builtin_amdgcn_s_barrier();
    __builtin_amdgcn_s_setprio(1);
    if (!vswap) {
#pragma unroll
      for (int kh = 0; kh < 2; ++kh)
#pragma unroll
        for (int m = 0; m < 4; ++m)
#pragma unroll
          for (int n = 0; n < 4; ++n)
            acc[m + 4][n] = __builtin_amdgcn_mfma_f32_16x16x32_bf16(
                afr[m][kh], bfrag[n][kh], acc[m + 4][n], 0, 0, 0);
    } else {
#pragma unroll
      for (int kh = 0; kh < 2; ++kh)
#pragma unroll
        for (int m = 0; m < 4; ++m)
#pragma unroll
          for (int n = 0; n < 4; ++n)
            acc[m + 4][n] = __builtin_amdgcn_mfma_f32_16x16x32_bf16(
                bfrag[n][kh], afr[m][kh], acc[m + 4][n], 0, 0, 0);
    }
    __builtin_amdgcn_s_setprio(0);
    if (t < NT - 2)       asm volatile("s_waitcnt vmcnt(4)" ::: "memory");
    else if (t == NT - 2) asm volatile("s_waitcnt vmcnt(0)" ::: "memory");
    __builtin_amdgcn_s_barrier();
  };

  // prologue: A(0)->buf0, B(0)->buf0, B(1)->buf1; wait oldest 8 (A0,B0)
#pragma unroll
  for (int i = 0; i < 4; ++i) {
    gload_lds16(pA[i], (void*)&As[0][ldsOff[i]]); pA[i] += 64;
    gload_lds16(pB[i], (void*)&Bs[0][ldsOff[i]]); pB[i] += 64;
  }
#pragma unroll
  for (int i = 0; i < 4; ++i) {
    gload_lds16(pB[i], (void*)&Bs[1][ldsOff[i]]); pB[i] += 64;
  }
  asm volatile("s_waitcnt vmcnt(4)" ::: "memory");
  __builtin_amdgcn_s_barrier();

  for (int t = 0; t < NT; t += 2) {
    tile_body(t,     std::integral_constant<int, 0>{});
    tile_body(t + 1, std::integral_constant<int, 1>{});
  }

  if constexpr (EPI == 0) {
    if (vswap) {
#pragma unroll
      for (int m = 0; m < 8; ++m) {
        const int nrow = rowBase + wr * 128 + m * 16 + l15;
        const int b = nrow >> 10, nn = nrow & 1023;
#pragma unroll
        for (int n = 0; n < 4; ++n) {
#pragma unroll
          for (int fr = 0; fr < 4; ++fr) {
            const int hk = (colBase - 2 * CD) + wc * 64 + n * 16 + lg * 4 + fr;
            const float v = acc[m][n][fr] + bias2[hk];
            const int h = hk >> 6, kk = hk & 63;
            dst2[((size_t)(b * CH + h) * CK + kk) * CN + nn] = __float2bfloat16(v);
          }
        }
      }
    } else {
      const int which = colBase / CD;  // 0=Q, 1=K
#pragma unroll
      for (int m = 0; m < 8; ++m) {
#pragma unroll
        for (int n = 0; n < 4; ++n) {
          const int col = colBase + wc * 64 + n * 16 + l15;
          const int hk = col - which * CD;
          const float bias = (which == 0) ? bias0[hk] * 0.125f : bias1[hk];
          bf16* dst = (which == 0) ? dst0 : dst1;
          const int h = hk >> 6, kk = hk & 63;
#pragma unroll
          for (int fr = 0; fr < 4; ++fr) {
            const int row = rowBase + wr * 128 + m * 16 + lg * 4 + fr;
            const int b = row >> 10, nn = row & 1023;
            dst[(((size_t)(b * CH + h)) * CN + nn) * CK + kk] =
                __float2bfloat16(acc[m][n][fr] + bias);
          }
        }
      }
    }
  } else {  // EPI == 2: +bias, exact GELU -> bf16 [*, CF]
#pragma unroll
    for (int m = 0; m < 8; ++m) {
#pragma unroll
      for (int n = 0; n < 4; ++n) {
        const int col = colBase + wc * 64 + n * 16 + l15;
        const float bias = bias0[col];
#pragma unroll
        for (int fr = 0; fr < 4; ++fr) {
          const int row = rowBase + wr * 128 + m * 16 + lg * 4 + fr;
          const float v = acc[m][n][fr] + bias;
          const float gel = 0.5f * v * (1.0f + erff(v * 0.70710678118654752f));
          dst0[(size_t)row * CF + col] = __float2bfloat16(gel);
        }
      }
    }
  }
}

// ---------------------------------------------------------------- GEMM 128²
// (m97 structure, for the narrow N=768 GEMMs). EPI 1: +bias +resid, fp32 out.
template <int EPI>
__global__ __launch_bounds__(256) void gemm_bf16_kernel(
    const bf16* __restrict__ A, const bf16* __restrict__ Bt, int Kd, int nbx,
    float* __restrict__ outF, const float* __restrict__ bias0,
    const float* __restrict__ resid) {
  __shared__ __align__(16) bf16 As[128 * 32];
  __shared__ __align__(16) bf16 Bs[128 * 32];
  const int tid = threadIdx.x;
  const int w = tid >> 6, l = tid & 63;
  const int wr = w >> 1, wc = w & 1;
  const int l15 = l & 15, lg = l >> 4;
  const int L = blockIdx.x;
  const int cpx = gridDim.x >> 3;
  const int g = (L & 7) * cpx + (L >> 3);
  const int by = g / nbx, bx = g - by * nbx;
  const int rowBase = by * 128;
  const int colBase = bx * 128;

  f32x4 acc[4][4];
#pragma unroll
  for (int i = 0; i < 4; ++i)
#pragma unroll
    for (int j = 0; j < 4; ++j)
#pragma unroll
      for (int r = 0; r < 4; ++r) acc[i][j][r] = 0.f;

  for (int k0 = 0; k0 < Kd; k0 += 32) {
    __syncthreads();
#pragma unroll
    for (int i = 0; i < 2; ++i) {
      const int c = w * 128 + i * 64 + l;
      const int r = c >> 2, cc = c & 3;
      gload_lds16(A + (size_t)(rowBase + r) * Kd + k0 + cc * 8,
                  (void*)&As[(w * 128 + i * 64) * 8]);
      gload_lds16(Bt + (size_t)(colBase + r) * Kd + k0 + cc * 8,
                  (void*)&Bs[(w * 128 + i * 64) * 8]);
    }
    __syncthreads();
    short8 af[4], bfr[4];
#pragma unroll
    for (int fm = 0; fm < 4; ++fm)
      af[fm] = *reinterpret_cast<const short8*>(
          &As[(wr * 64 + fm * 16 + l15) * 32 + lg * 8]);
#pragma unroll
    for (int fn = 0; fn < 4; ++fn)
      bfr[fn] = *reinterpret_cast<const short8*>(
          &Bs[(wc * 64 + fn * 16 + l15) * 32 + lg * 8]);
#pragma unroll
    for (int fm = 0; fm < 4; ++fm)
#pragma unroll
      for (int fn = 0; fn < 4; ++fn)
        acc[fm][fn] = __builtin_amdgcn_mfma_f32_16x16x32_bf16(
            af[fm], bfr[fn], acc[fm][fn], 0, 0, 0);
  }

  const int mrow0 = rowBase + wr * 64;
  const int ncol0 = colBase + wc * 64;
#pragma unroll
  for (int fm = 0; fm < 4; ++fm) {
#pragma unroll
    for (int fn = 0; fn < 4; ++fn) {
      const int col = ncol0 + fn * 16 + l15;
#pragma unroll
      for (int fr = 0; fr < 4; ++fr) {
        const int row = mrow0 + fm * 16 + lg * 4 + fr;
        float v = acc[fm][fn][fr];
        v += bias0[col] + resid[(size_t)row * CD + col];
        outF[(size_t)row * CD + col] = v;
      }
    }
  }
}

// ---------------------------------------------------------------- attention
// R9 proven: block-staged flash attention. grid 1536, head XCD-affinity
// (bh=(i&7)+8*(i>>7), qb=(i>>3)&15). 4 waves x 16 q-rows share K/V tiles
// staged via global_load_lds + T2 swizzle; double-buffered; swapped QK^T,
// defer-max, per-lane lsum. Q pre-scaled 1/8.
__global__ __launch_bounds__(256) void attn_kernel(
    const bf16* __restrict__ Qb, const bf16* __restrict__ Kb,
    const bf16* __restrict__ Vtb, bf16* __restrict__ ctxb) {
  __shared__ __align__(16) bf16 Ks[2][64 * 64];  // [m][k-dim], 8 KB/buf
  __shared__ __align__(16) bf16 Vs[2][64 * 64];  // Vt tile [d][key], 8 KB/buf
  __shared__ __align__(16) bf16 Ps[4][16][72];   // per-wave P tile

  const int tid = threadIdx.x;
  const int w = tid >> 6, l = tid & 63;
  const int l15 = l & 15, lg = l >> 4;
  const int i = blockIdx.x;
  const int bh = (i & 7) + 8 * (i >> 7);  // head 0..95, fixed per XCD
  const int qb = (i >> 3) & 15;           // 64-row q block
  const int b = bh / CH, h = bh - b * CH;
  const bf16* Qh  = Qb  + (size_t)bh * CN * CK;
  const bf16* Kh  = Kb  + (size_t)bh * CN * CK;
  const bf16* Vth = Vtb + (size_t)bh * CK * CN;
  const int q0 = qb * 64 + w * 16;

  auto stageKV = [&](int kt, int buf) {
#pragma unroll
    for (int ii = 0; ii < 2; ++ii) {
      const int s = ii * 256 + w * 64 + l;
      const int row = s >> 3, c16 = s & 7;
      const int gc16 = c16 ^ (row & 7);
      gload_lds16(Kh + (size_t)(kt * 64 + row) * CK + gc16 * 8,
                  (void*)&Ks[buf][(ii * 256 + w * 64) * 8]);
      gload_lds16(Vth + (size_t)row * CN + kt * 64 + gc16 * 8,
                  (void*)&Vs[buf][(ii * 256 + w * 64) * 8]);
    }
  };
  auto read_k = [&](int buf, int mb, int c) -> short8 {
    const int row = mb * 16 + l15;
    const int c16 = (c * 4 + lg) ^ (l15 & 7);
    return *reinterpret_cast<const short8*>(&Ks[buf][row * 64 + c16 * 8]);
  };
  auto read_v = [&](int buf, int kb, int c) -> short8 {
    const int row = kb * 16 + l15;
    const int c16 = (c * 4 + lg) ^ (l15 & 7);
    return *reinterpret_cast<const short8*>(&Vs[buf][row * 64 + c16 * 8]);
  };

  short8 aq[2];
#pragma unroll
  for (int c = 0; c < 2; ++c)
    aq[c] = *reinterpret_cast<const short8*>(
        Qh + (size_t)(q0 + l15) * CK + c * 32 + lg * 8);

  f32x4 oacc[4];
  float mreg = -INFINITY, lpart = 0.f;
#pragma unroll
  for (int kb = 0; kb < 4; ++kb)
#pragma unroll
    for (int r = 0; r < 4; ++r) oacc[kb][r] = 0.f;

  stageKV(0, 0);
  asm volatile("s_waitcnt vmcnt(0)" ::: "memory");
  __builtin_amdgcn_s_barrier();

#pragma unroll 1
  for (int kt = 0; kt < 16; ++kt) {
    const int buf = kt & 1;
    if (kt < 15) stageKV(kt + 1, buf ^ 1);

    short8 kf[4][2];
#pragma unroll
    for (int mb = 0; mb < 4; ++mb)
#pragma unroll
      for (int c = 0; c < 2; ++c) kf[mb][c] = read_k(buf, mb, c);

    f32x4 sacc[4];
    __builtin_amdgcn_s_setprio(1);
#pragma unroll
    for (int mb = 0; mb < 4; ++mb) {
      f32x4 z;
#pragma unroll
      for (int r = 0; r < 4; ++r) z[r] = 0.f;
      z = __builtin_amdgcn_mfma_f32_16x16x32_bf16(kf[mb][0], aq[0], z, 0, 0, 0);
      z = __builtin_amdgcn_mfma_f32_16x16x32_bf16(kf[mb][1], aq[1], z, 0, 0, 0);
      sacc[mb] = z;
    }
    __builtin_amdgcn_s_setprio(0);

    float mx = sacc[0][0];
#pragma unroll
    for (int mb = 0; mb < 4; ++mb)
#pragma unroll
      for (int r = 0; r < 4; ++r) mx = fmaxf(mx, sacc[mb][r]);
    mx = fmaxf(mx, __shfl_xor(mx, 16));
    mx = fmaxf(mx, __shfl_xor(mx, 32));
    if (!__all(mx - mreg <= 8.f)) {
      const float mn = fmaxf(mreg, mx);
      const float alpha = __expf(mreg - mn);
      float alr[4];
#pragma unroll
      for (int r = 0; r < 4; ++r) alr[r] = __shfl(alpha, lg * 4 + r);
#pragma unroll
      for (int kb = 0; kb < 4; ++kb)
#pragma unroll
        for (int r = 0; r < 4; ++r) oacc[kb][r] *= alr[r];
      lpart *= alpha;
      mreg = mn;
    }
#pragma unroll
    for (int mb = 0; mb < 4; ++mb)
#pragma unroll
      for (int r = 0; r < 4; ++r) {
        const float p = __expf(sacc[mb][r] - mreg);
        sacc[mb][r] = p;
        lpart += p;
      }

    short8 vf[4][2];
#pragma unroll
    for (int kb = 0; kb < 4; ++kb)
#pragma unroll
      for (int c = 0; c < 2; ++c) vf[kb][c] = read_v(buf, kb, c);

#pragma unroll
    for (int mb = 0; mb < 4; ++mb) {
      bf16 tmp[4];
#pragma unroll
      for (int r = 0; r < 4; ++r) tmp[r] = __float2bfloat16(sacc[mb][r]);
      *reinterpret_cast<uint2*>(&Ps[w][l15][mb * 16 + lg * 4]) =
          *reinterpret_cast<const uint2*>(tmp);
    }
    const short8 pa0 = *reinterpret_cast<const short8*>(&Ps[w][l15][lg * 8]);
    const short8 pa1 = *reinterpret_cast<const short8*>(&Ps[w][l15][32 + lg * 8]);

    __builtin_amdgcn_s_setprio(1);
#pragma unroll
    for (int kb = 0; kb < 4; ++kb) {
      oacc[kb] = __builtin_amdgcn_mfma_f32_16x16x32_bf16(pa0, vf[kb][0],
                                                         oacc[kb], 0, 0, 0);
      oacc[kb] = __builtin_amdgcn_mfma_f32_16x16x32_bf16(pa1, vf[kb][1],
                                                         oacc[kb], 0, 0, 0);
    }
    __builtin_amdgcn_s_setprio(0);

    asm volatile("s_waitcnt vmcnt(0)" ::: "memory");
    __builtin_amdgcn_s_barrier();
  }

  float lsum = lpart;
  lsum += __shfl_xor(lsum, 16);
  lsum += __shfl_xor(lsum, 32);

#pragma unroll
  for (int r = 0; r < 4; ++r) {
    const float inv = 1.f / __shfl(lsum, lg * 4 + r);
    const int n = q0 + lg * 4 + r;
    bf16* dst = ctxb + ((size_t)(b * CN + n)) * CD + h * CK;
#pragma unroll
    for (int kb = 0; kb < 4; ++kb)
      dst[kb * 16 + l15] = __float2bfloat16(oacc[kb][r] * inv);
  }
}

// ---------------------------------------------------------------- launcher
extern "C" void kernel_launch(void* const* d_in, const int* in_sizes, int n_in,
                              void* d_out, int out_size, void* d_ws,
                              size_t ws_size, hipStream_t stream) {
  const float* x    = (const float*)d_in[0];
  const float* ln1g = (const float*)d_in[1];
  const float* ln1b = (const float*)d_in[2];
  const float* wq   = (const float*)d_in[3];
  const float* bq   = (const float*)d_in[4];
  const float* wk   = (const float*)d_in[5];
  const float* bk   = (const float*)d_in[6];
  const float* wv   = (const float*)d_in[7];
  const float* bv   = (const float*)d_in[8];
  const float* wo   = (const float*)d_in[9];
  const float* bo   = (const float*)d_in[10];
  const float* ln2g = (const float*)d_in[11];
  const float* ln2b = (const float*)d_in[12];
  const float* w1   = (const float*)d_in[13];
  const float* b1   = (const float*)d_in[14];
  const float* w2   = (const float*)d_in[15];
  const float* b2   = (const float*)d_in[16];

  char* ws = (char*)d_ws;
  bf16* wqkvt = (bf16*)(ws + 0);
  bf16* wot   = (bf16*)(ws + 3538944);
  bf16* w1t   = (bf16*)(ws + 4718592);
  bf16* w2t   = (bf16*)(ws + 9437184);
  bf16* h1    = (bf16*)(ws + 14155776);
  bf16* Qbuf  = (bf16*)(ws + 26738688);
  bf16* Kbuf  = (bf16*)(ws + 39321600);
  bf16* Vtbuf = (bf16*)(ws + 51904512);
  bf16* gb    = (bf16*)(ws + 14155776);  // reuse h1+Q+K+V region
  bf16* ctxb  = (bf16*)(ws + 64487424);
  bf16* h2    = (bf16*)(ws + 64487424);  // reuse ctx region
  float* outb = (float*)(ws + 77070336);
  float* y    = (float*)d_out;

  transpose_f32_bf16<<<dim3(24, 24), 256, 0, stream>>>(wq, wqkvt, 768, 768, 0.125f);
  transpose_f32_bf16<<<dim3(24, 24), 256, 0, stream>>>(wk, wqkvt + 768 * 768, 768, 768, 1.f);
  transpose_f32_bf16<<<dim3(24, 24), 256, 0, stream>>>(wv, wqkvt + 2 * 768 * 768, 768, 768, 1.f);
  transpose_f32_bf16<<<dim3(24, 24), 256, 0, stream>>>(wo, wot, 768, 768, 1.f);
  transpose_f32_bf16<<<dim3(96, 24), 256, 0, stream>>>(w1, w1t, 768, 3072, 1.f);
  transpose_f32_bf16<<<dim3(24, 96), 256, 0, stream>>>(w2, w2t, 3072, 768, 1.f);

  ln_bf16<<<ROWS, 256, 0, stream>>>(x, ln1g, ln1b, h1);

  // QKV: 256² 2-phase, grid 32x9 = 288 (%8==0)
  gemm256_kernel<0><<<(ROWS / 256) * 9, 512, 0, stream>>>(
      h1, wqkvt, 768, 9, Qbuf, Kbuf, Vtbuf, bq, bk, bv);

  attn_kernel<<<CB * CH * 16, 256, 0, stream>>>(Qbuf, Kbuf, Vtbuf, ctxb);

  gemm_bf16_kernel<1><<<6 * (ROWS / 128), 256, 0, stream>>>(
      ctxb, wot, 768, 6, outb, bo, x);

  ln_bf16<<<ROWS, 256, 0, stream>>>(outb, ln2g, ln2b, h2);

  // MLP1: 256² 2-phase, grid 32x12 = 384 (%8==0)
  gemm256_kernel<2><<<(ROWS / 256) * 12, 512, 0, stream>>>(
      h2, w1t, 768, 12, gb, nullptr, nullptr, b1, nullptr, nullptr);

  gemm_bf16_kernel<1><<<6 * (ROWS / 128), 256, 0, stream>>>(
      gb, w2t, 3072, 6, y, b2, outb);

  (void)in_sizes; (void)n_in; (void)out_size; (void)ws_size;
}

// Round 13
// 329.660 us; speedup vs baseline: 2.5017x; 1.4428x over previous
//
#include <hip/hip_runtime.h>
#include <hip/hip_bf16.h>
#include <math.h>

typedef __hip_bfloat16 bf16;
typedef __attribute__((ext_vector_type(8))) short short8;   // 8 bf16 = 4 VGPRs
typedef __attribute__((ext_vector_type(4))) float f32x4;

#define DEV __device__ __forceinline__

// problem constants
constexpr int CB = 8, CN = 1024, CD = 768, CH = 12, CK = 64, CF = 3072;
constexpr int ROWS = CB * CN;  // 8192

// ---------------------------------------------------------------- utilities
DEV void gload_lds16(const void* g, void* l) {
  __builtin_amdgcn_global_load_lds(
      (const __attribute__((address_space(1))) void*)g,
      (__attribute__((address_space(3))) void*)l, 16, 0, 0);
}

// ------------------------------------------------------- weight prep (T + cast)
__global__ __launch_bounds__(256) void transpose_f32_bf16(
    const float* __restrict__ in, bf16* __restrict__ out, int R, int C,
    float scale) {
  __shared__ float tile[32][33];
  const int tx = threadIdx.x & 31, ty = threadIdx.x >> 5;  // 32 x 8
  const int c0 = blockIdx.x * 32, r0 = blockIdx.y * 32;
#pragma unroll
  for (int i = 0; i < 4; ++i)
    tile[ty + i * 8][tx] = in[(size_t)(r0 + ty + i * 8) * C + c0 + tx];
  __syncthreads();
#pragma unroll
  for (int i = 0; i < 4; ++i)
    out[(size_t)(c0 + ty + i * 8) * R + r0 + tx] =
        __float2bfloat16(tile[tx][ty + i * 8] * scale);
}

// ---------------------------------------------------------------- LayerNorm
__global__ __launch_bounds__(256) void ln_bf16(
    const float* __restrict__ in, const float* __restrict__ gamma,
    const float* __restrict__ beta, bf16* __restrict__ out) {
  const int row = blockIdx.x;
  const int tid = threadIdx.x;
  const float* x = in + (size_t)row * CD;
  const float v0 = x[tid], v1 = x[tid + 256], v2 = x[tid + 512];
  float s = v0 + v1 + v2;
  float q = v0 * v0 + v1 * v1 + v2 * v2;
#pragma unroll
  for (int off = 32; off > 0; off >>= 1) {
    s += __shfl_xor(s, off);
    q += __shfl_xor(q, off);
  }
  __shared__ float sm[8];
  const int w = tid >> 6, l = tid & 63;
  if (l == 0) { sm[w] = s; sm[4 + w] = q; }
  __syncthreads();
  s = sm[0] + sm[1] + sm[2] + sm[3];
  q = sm[4] + sm[5] + sm[6] + sm[7];
  const float mean = s * (1.f / CD);
  const float var = q * (1.f / CD) - mean * mean;
  const float rs = rsqrtf(var + 1e-5f);
  bf16* o = out + (size_t)row * CD;
  o[tid]       = __float2bfloat16((v0 - mean) * rs * gamma[tid]       + beta[tid]);
  o[tid + 256] = __float2bfloat16((v1 - mean) * rs * gamma[tid + 256] + beta[tid + 256]);
  o[tid + 512] = __float2bfloat16((v2 - mean) * rs * gamma[tid + 512] + beta[tid + 512]);
}

// ------------------------------------------- 256x256 GEMM, thin barriers
// R13 = R9's proven 4-phase kernel (VGPR-112 profile, no spill) with the
// intra-tile barriers THINNED to the correctness-minimal set:
//   - reads: bfrag (all B) @ph0, afr quad per phase; writers this tile:
//     A(t+1)->buf^1 (never conflicts), B(t+2)->Bs[buf] (conflicts only
//     with ph0's B reads).
//   - so: ONE mid-barrier after ph0's MFMA (all waves consumed B reads
//     before any wave can issue B(t+2) at ph2/ph3), ONE tile-end
//     vmcnt+barrier (publishes staged tiles). 2 barriers/K-tile (was 8).
// Stage slots (R9): p0 A(t+1)h0, p1 A(t+1)h1, p2 B(t+2)h0, p3 B(t+2)h1.
// vmcnt(4) at tile end: outstanding newest 4 = B(t+2) -> tile t+1 landed.
// t==NT-2: vmcnt(0). Prologue: A(0),B(0),B(1) + vmcnt(4).
// T2 swizzle: inverse-swizzled GLOBAL source + swizzled ds_read (rule #21).
template <int EPI>
__global__ __launch_bounds__(512, 2) void gemm256_kernel(
    const bf16* __restrict__ A, const bf16* __restrict__ Bt, int Kd, int nbx,
    bf16* __restrict__ dst0, bf16* __restrict__ dst1, bf16* __restrict__ dst2,
    const float* __restrict__ bias0, const float* __restrict__ bias1,
    const float* __restrict__ bias2) {
  __shared__ __align__(16) bf16 As[2][2][128 * 64];  // 64 KB
  __shared__ __align__(16) bf16 Bs[2][2][128 * 64];  // 64 KB

  const int tid = threadIdx.x;
  const int w = tid >> 6, l = tid & 63;
  const int wr = w >> 2, wc = w & 3;  // 2 x 4 wave grid
  const int l15 = l & 15, lg = l >> 4;

  const int L = blockIdx.x;
  const int cpx = gridDim.x >> 3;
  const int g = (L & 7) * cpx + (L >> 3);   // XCD swizzle (grid % 8 == 0)
  const int by = g / nbx, bx = g - by * nbx;
  const int rowBase = by * 256, colBase = bx * 256;
  const bool vswap = (EPI == 0) && (colBase >= 2 * CD);
  const int NT = Kd >> 6;

  auto stage = [&](int t, int q) {
    const int buf = t & 1;
    const int half = q & 1;
    const bf16* src = (q < 2) ? A : Bt;
    const int base = ((q < 2) ? rowBase : colBase) + half * 128;
    const int k0 = t * 64;
    bf16* lds = (q < 2) ? &As[buf][half][0] : &Bs[buf][half][0];
#pragma unroll
    for (int i = 0; i < 2; ++i) {
      const int s = i * 512 + tid;           // 16B slot 0..1023
      const int row = s >> 3, c16 = s & 7;
      const int gc16 = c16 ^ (row & 7);      // inverse swizzle on source
      gload_lds16(src + (size_t)(base + row) * Kd + k0 + gc16 * 8,
                  (void*)&lds[(i * 512 + w * 64) * 8]);
    }
  };
  auto read_a = [&](int buf, int m, int kh) -> short8 {
    const int row = m * 16 + l15;
    const int c16 = (kh * 4 + lg) ^ (l15 & 7);  // swizzled read
    return *reinterpret_cast<const short8*>(&As[buf][wr][row * 64 + c16 * 8]);
  };
  auto read_b = [&](int buf, int n, int kh) -> short8 {
    const int c = wc * 64 + n * 16 + l15;
    const int half = c >> 7, row = c & 127;
    const int c16 = (kh * 4 + lg) ^ (l15 & 7);
    return *reinterpret_cast<const short8*>(&Bs[buf][half][row * 64 + c16 * 8]);
  };

  f32x4 acc[8][4];
#pragma unroll
  for (int m = 0; m < 8; ++m)
#pragma unroll
    for (int n = 0; n < 4; ++n)
#pragma unroll
      for (int r = 0; r < 4; ++r) acc[m][n][r] = 0.f;

  // prologue: A(0),B(0) then B(1); wait oldest 8 (tile0), leave B(1) in flight
  stage(0, 0); stage(0, 1); stage(0, 2); stage(0, 3);
  stage(1, 2); stage(1, 3);
  asm volatile("s_waitcnt vmcnt(4)" ::: "memory");
  __builtin_amdgcn_s_barrier();

  short8 bfrag[4][2];
  for (int t = 0; t < NT; ++t) {
    const int buf = t & 1;
#pragma unroll
    for (int p = 0; p < 4; ++p) {
      short8 afr[2][2];
      if (p == 0) {
#pragma unroll
        for (int n = 0; n < 4; ++n)
#pragma unroll
          for (int kh = 0; kh < 2; ++kh) bfrag[n][kh] = read_b(buf, n, kh);
      }
#pragma unroll
      for (int mm = 0; mm < 2; ++mm)
#pragma unroll
        for (int kh = 0; kh < 2; ++kh) afr[mm][kh] = read_a(buf, 2 * p + mm, kh);
      // stage slots (liveness-safe: A->buf^1 anytime; B(t+2) only after
      // the mid-barrier, and p2/p3 are after it)
      if (p == 0 && t + 1 < NT) stage(t + 1, 0);
      if (p == 1 && t + 1 < NT) stage(t + 1, 1);
      if (p == 2 && t + 2 < NT) stage(t + 2, 2);
      if (p == 3 && t + 2 < NT) stage(t + 2, 3);
      __builtin_amdgcn_s_setprio(1);
      if (!vswap) {
#pragma unroll
        for (int kh = 0; kh < 2; ++kh)
#pragma unroll
          for (int mm = 0; mm < 2; ++mm)
#pragma unroll
            for (int n = 0; n < 4; ++n)
              acc[2 * p + mm][n] = __builtin_amdgcn_mfma_f32_16x16x32_bf16(
                  afr[mm][kh], bfrag[n][kh], acc[2 * p + mm][n], 0, 0, 0);
      } else {
#pragma unroll
        for (int kh = 0; kh < 2; ++kh)
#pragma unroll
          for (int mm = 0; mm < 2; ++mm)
#pragma unroll
            for (int n = 0; n < 4; ++n)
              acc[2 * p + mm][n] = __builtin_amdgcn_mfma_f32_16x16x32_bf16(
                  bfrag[n][kh], afr[mm][kh], acc[2 * p + mm][n], 0, 0, 0);
      }
      __builtin_amdgcn_s_setprio(0);
      // thin barriers: mid-barrier after ph0's MFMA (B reads consumed by
      // every wave before any B(t+2) DMA can land); tile-end barrier below.
      if (p == 0) __builtin_amdgcn_s_barrier();
      if (p == 3) {
        if (t < NT - 2)       asm volatile("s_waitcnt vmcnt(4)" ::: "memory");
        else if (t == NT - 2) asm volatile("s_waitcnt vmcnt(0)" ::: "memory");
        __builtin_amdgcn_s_barrier();
      }
    }
  }

  if constexpr (EPI == 0) {
    if (vswap) {
#pragma unroll
      for (int m = 0; m < 8; ++m) {
        const int nrow = rowBase + wr * 128 + m * 16 + l15;
        const int b = nrow >> 10, nn = nrow & 1023;
#pragma unroll
        for (int n = 0; n < 4; ++n) {
#pragma unroll
          for (int fr = 0; fr < 4; ++fr) {
            const int hk = (colBase - 2 * CD) + wc * 64 + n * 16 + lg * 4 + fr;
            const float v = acc[m][n][fr] + bias2[hk];
            const int h = hk >> 6, kk = hk & 63;
            dst2[((size_t)(b * CH + h) * CK + kk) * CN + nn] = __float2bfloat16(v);
          }
        }
      }
    } else {
      const int which = colBase / CD;  // 0=Q, 1=K
#pragma unroll
      for (int m = 0; m < 8; ++m) {
#pragma unroll
        for (int n = 0; n < 4; ++n) {
          const int col = colBase + wc * 64 + n * 16 + l15;
          const int hk = col - which * CD;
          const float bias = (which == 0) ? bias0[hk] * 0.125f : bias1[hk];
          bf16* dst = (which == 0) ? dst0 : dst1;
          const int h = hk >> 6, kk = hk & 63;
#pragma unroll
          for (int fr = 0; fr < 4; ++fr) {
            const int row = rowBase + wr * 128 + m * 16 + lg * 4 + fr;
            const int b = row >> 10, nn = row & 1023;
            dst[(((size_t)(b * CH + h)) * CN + nn) * CK + kk] =
                __float2bfloat16(acc[m][n][fr] + bias);
          }
        }
      }
    }
  } else {  // EPI == 2: +bias, exact GELU -> bf16 [*, CF]
#pragma unroll
    for (int m = 0; m < 8; ++m) {
#pragma unroll
      for (int n = 0; n < 4; ++n) {
        const int col = colBase + wc * 64 + n * 16 + l15;
        const float bias = bias0[col];
#pragma unroll
        for (int fr = 0; fr < 4; ++fr) {
          const int row = rowBase + wr * 128 + m * 16 + lg * 4 + fr;
          const float v = acc[m][n][fr] + bias;
          const float gel = 0.5f * v * (1.0f + erff(v * 0.70710678118654752f));
          dst0[(size_t)row * CF + col] = __float2bfloat16(gel);
        }
      }
    }
  }
}

// ---------------------------------------------------------------- GEMM 128²
// (m97 structure, for the narrow N=768 GEMMs). EPI 1: +bias +resid, fp32 out.
template <int EPI>
__global__ __launch_bounds__(256) void gemm_bf16_kernel(
    const bf16* __restrict__ A, const bf16* __restrict__ Bt, int Kd, int nbx,
    float* __restrict__ outF, const float* __restrict__ bias0,
    const float* __restrict__ resid) {
  __shared__ __align__(16) bf16 As[128 * 32];
  __shared__ __align__(16) bf16 Bs[128 * 32];
  const int tid = threadIdx.x;
  const int w = tid >> 6, l = tid & 63;
  const int wr = w >> 1, wc = w & 1;
  const int l15 = l & 15, lg = l >> 4;
  const int L = blockIdx.x;
  const int cpx = gridDim.x >> 3;
  const int g = (L & 7) * cpx + (L >> 3);
  const int by = g / nbx, bx = g - by * nbx;
  const int rowBase = by * 128;
  const int colBase = bx * 128;

  f32x4 acc[4][4];
#pragma unroll
  for (int i = 0; i < 4; ++i)
#pragma unroll
    for (int j = 0; j < 4; ++j)
#pragma unroll
      for (int r = 0; r < 4; ++r) acc[i][j][r] = 0.f;

  for (int k0 = 0; k0 < Kd; k0 += 32) {
    __syncthreads();
#pragma unroll
    for (int i = 0; i < 2; ++i) {
      const int c = w * 128 + i * 64 + l;
      const int r = c >> 2, cc = c & 3;
      gload_lds16(A + (size_t)(rowBase + r) * Kd + k0 + cc * 8,
                  (void*)&As[(w * 128 + i * 64) * 8]);
      gload_lds16(Bt + (size_t)(colBase + r) * Kd + k0 + cc * 8,
                  (void*)&Bs[(w * 128 + i * 64) * 8]);
    }
    __syncthreads();
    short8 af[4], bfr[4];
#pragma unroll
    for (int fm = 0; fm < 4; ++fm)
      af[fm] = *reinterpret_cast<const short8*>(
          &As[(wr * 64 + fm * 16 + l15) * 32 + lg * 8]);
#pragma unroll
    for (int fn = 0; fn < 4; ++fn)
      bfr[fn] = *reinterpret_cast<const short8*>(
          &Bs[(wc * 64 + fn * 16 + l15) * 32 + lg * 8]);
#pragma unroll
    for (int fm = 0; fm < 4; ++fm)
#pragma unroll
      for (int fn = 0; fn < 4; ++fn)
        acc[fm][fn] = __builtin_amdgcn_mfma_f32_16x16x32_bf16(
            af[fm], bfr[fn], acc[fm][fn], 0, 0, 0);
  }

  const int mrow0 = rowBase + wr * 64;
  const int ncol0 = colBase + wc * 64;
#pragma unroll
  for (int fm = 0; fm < 4; ++fm) {
#pragma unroll
    for (int fn = 0; fn < 4; ++fn) {
      const int col = ncol0 + fn * 16 + l15;
#pragma unroll
      for (int fr = 0; fr < 4; ++fr) {
        const int row = mrow0 + fm * 16 + lg * 4 + fr;
        float v = acc[fm][fn][fr];
        v += bias0[col] + resid[(size_t)row * CD + col];
        outF[(size_t)row * CD + col] = v;
      }
    }
  }
}

// ---------------------------------------------------------------- attention
// R9 proven: block-staged flash attention. grid 1536, head XCD-affinity
// (bh=(i&7)+8*(i>>7), qb=(i>>3)&15). 4 waves x 16 q-rows share K/V tiles
// staged via global_load_lds + T2 swizzle; double-buffered; swapped QK^T,
// defer-max, per-lane lsum. Q pre-scaled 1/8.
__global__ __launch_bounds__(256) void attn_kernel(
    const bf16* __restrict__ Qb, const bf16* __restrict__ Kb,
    const bf16* __restrict__ Vtb, bf16* __restrict__ ctxb) {
  __shared__ __align__(16) bf16 Ks[2][64 * 64];  // [m][k-dim], 8 KB/buf
  __shared__ __align__(16) bf16 Vs[2][64 * 64];  // Vt tile [d][key], 8 KB/buf
  __shared__ __align__(16) bf16 Ps[4][16][72];   // per-wave P tile

  const int tid = threadIdx.x;
  const int w = tid >> 6, l = tid & 63;
  const int l15 = l & 15, lg = l >> 4;
  const int i = blockIdx.x;
  const int bh = (i & 7) + 8 * (i >> 7);  // head 0..95, fixed per XCD
  const int qb = (i >> 3) & 15;           // 64-row q block
  const int b = bh / CH, h = bh - b * CH;
  const bf16* Qh  = Qb  + (size_t)bh * CN * CK;
  const bf16* Kh  = Kb  + (size_t)bh * CN * CK;
  const bf16* Vth = Vtb + (size_t)bh * CK * CN;
  const int q0 = qb * 64 + w * 16;

  auto stageKV = [&](int kt, int buf) {
#pragma unroll
    for (int ii = 0; ii < 2; ++ii) {
      const int s = ii * 256 + w * 64 + l;
      const int row = s >> 3, c16 = s & 7;
      const int gc16 = c16 ^ (row & 7);
      gload_lds16(Kh + (size_t)(kt * 64 + row) * CK + gc16 * 8,
                  (void*)&Ks[buf][(ii * 256 + w * 64) * 8]);
      gload_lds16(Vth + (size_t)row * CN + kt * 64 + gc16 * 8,
                  (void*)&Vs[buf][(ii * 256 + w * 64) * 8]);
    }
  };
  auto read_k = [&](int buf, int mb, int c) -> short8 {
    const int row = mb * 16 + l15;
    const int c16 = (c * 4 + lg) ^ (l15 & 7);
    return *reinterpret_cast<const short8*>(&Ks[buf][row * 64 + c16 * 8]);
  };
  auto read_v = [&](int buf, int kb, int c) -> short8 {
    const int row = kb * 16 + l15;
    const int c16 = (c * 4 + lg) ^ (l15 & 7);
    return *reinterpret_cast<const short8*>(&Vs[buf][row * 64 + c16 * 8]);
  };

  short8 aq[2];
#pragma unroll
  for (int c = 0; c < 2; ++c)
    aq[c] = *reinterpret_cast<const short8*>(
        Qh + (size_t)(q0 + l15) * CK + c * 32 + lg * 8);

  f32x4 oacc[4];
  float mreg = -INFINITY, lpart = 0.f;
#pragma unroll
  for (int kb = 0; kb < 4; ++kb)
#pragma unroll
    for (int r = 0; r < 4; ++r) oacc[kb][r] = 0.f;

  stageKV(0, 0);
  asm volatile("s_waitcnt vmcnt(0)" ::: "memory");
  __builtin_amdgcn_s_barrier();

#pragma unroll 1
  for (int kt = 0; kt < 16; ++kt) {
    const int buf = kt & 1;
    if (kt < 15) stageKV(kt + 1, buf ^ 1);

    short8 kf[4][2];
#pragma unroll
    for (int mb = 0; mb < 4; ++mb)
#pragma unroll
      for (int c = 0; c < 2; ++c) kf[mb][c] = read_k(buf, mb, c);

    f32x4 sacc[4];
    __builtin_amdgcn_s_setprio(1);
#pragma unroll
    for (int mb = 0; mb < 4; ++mb) {
      f32x4 z;
#pragma unroll
      for (int r = 0; r < 4; ++r) z[r] = 0.f;
      z = __builtin_amdgcn_mfma_f32_16x16x32_bf16(kf[mb][0], aq[0], z, 0, 0, 0);
      z = __builtin_amdgcn_mfma_f32_16x16x32_bf16(kf[mb][1], aq[1], z, 0, 0, 0);
      sacc[mb] = z;
    }
    __builtin_amdgcn_s_setprio(0);

    float mx = sacc[0][0];
#pragma unroll
    for (int mb = 0; mb < 4; ++mb)
#pragma unroll
      for (int r = 0; r < 4; ++r) mx = fmaxf(mx, sacc[mb][r]);
    mx = fmaxf(mx, __shfl_xor(mx, 16));
    mx = fmaxf(mx, __shfl_xor(mx, 32));
    if (!__all(mx - mreg <= 8.f)) {
      const float mn = fmaxf(mreg, mx);
      const float alpha = __expf(mreg - mn);
      float alr[4];
#pragma unroll
      for (int r = 0; r < 4; ++r) alr[r] = __shfl(alpha, lg * 4 + r);
#pragma unroll
      for (int kb = 0; kb < 4; ++kb)
#pragma unroll
        for (int r = 0; r < 4; ++r) oacc[kb][r] *= alr[r];
      lpart *= alpha;
      mreg = mn;
    }
#pragma unroll
    for (int mb = 0; mb < 4; ++mb)
#pragma unroll
      for (int r = 0; r < 4; ++r) {
        const float p = __expf(sacc[mb][r] - mreg);
        sacc[mb][r] = p;
        lpart += p;
      }

    short8 vf[4][2];
#pragma unroll
    for (int kb = 0; kb < 4; ++kb)
#pragma unroll
      for (int c = 0; c < 2; ++c) vf[kb][c] = read_v(buf, kb, c);

#pragma unroll
    for (int mb = 0; mb < 4; ++mb) {
      bf16 tmp[4];
#pragma unroll
      for (int r = 0; r < 4; ++r) tmp[r] = __float2bfloat16(sacc[mb][r]);
      *reinterpret_cast<uint2*>(&Ps[w][l15][mb * 16 + lg * 4]) =
          *reinterpret_cast<const uint2*>(tmp);
    }
    const short8 pa0 = *reinterpret_cast<const short8*>(&Ps[w][l15][lg * 8]);
    const short8 pa1 = *reinterpret_cast<const short8*>(&Ps[w][l15][32 + lg * 8]);

    __builtin_amdgcn_s_setprio(1);
#pragma unroll
    for (int kb = 0; kb < 4; ++kb) {
      oacc[kb] = __builtin_amdgcn_mfma_f32_16x16x32_bf16(pa0, vf[kb][0],
                                                         oacc[kb], 0, 0, 0);
      oacc[kb] = __builtin_amdgcn_mfma_f32_16x16x32_bf16(pa1, vf[kb][1],
                                                         oacc[kb], 0, 0, 0);
    }
    __builtin_amdgcn_s_setprio(0);

    asm volatile("s_waitcnt vmcnt(0)" ::: "memory");
    __builtin_amdgcn_s_barrier();
  }

  float lsum = lpart;
  lsum += __shfl_xor(lsum, 16);
  lsum += __shfl_xor(lsum, 32);

#pragma unroll
  for (int r = 0; r < 4; ++r) {
    const float inv = 1.f / __shfl(lsum, lg * 4 + r);
    const int n = q0 + lg * 4 + r;
    bf16* dst = ctxb + ((size_t)(b * CN + n)) * CD + h * CK;
#pragma unroll
    for (int kb = 0; kb < 4; ++kb)
      dst[kb * 16 + l15] = __float2bfloat16(oacc[kb][r] * inv);
  }
}

// ---------------------------------------------------------------- launcher
extern "C" void kernel_launch(void* const* d_in, const int* in_sizes, int n_in,
                              void* d_out, int out_size, void* d_ws,
                              size_t ws_size, hipStream_t stream) {
  const float* x    = (const float*)d_in[0];
  const float* ln1g = (const float*)d_in[1];
  const float* ln1b = (const float*)d_in[2];
  const float* wq   = (const float*)d_in[3];
  const float* bq   = (const float*)d_in[4];
  const float* wk   = (const float*)d_in[5];
  const float* bk   = (const float*)d_in[6];
  const float* wv   = (const float*)d_in[7];
  const float* bv   = (const float*)d_in[8];
  const float* wo   = (const float*)d_in[9];
  const float* bo   = (const float*)d_in[10];
  const float* ln2g = (const float*)d_in[11];
  const float* ln2b = (const float*)d_in[12];
  const float* w1   = (const float*)d_in[13];
  const float* b1   = (const float*)d_in[14];
  const float* w2   = (const float*)d_in[15];
  const float* b2   = (const float*)d_in[16];

  char* ws = (char*)d_ws;
  bf16* wqkvt = (bf16*)(ws + 0);
  bf16* wot   = (bf16*)(ws + 3538944);
  bf16* w1t   = (bf16*)(ws + 4718592);
  bf16* w2t   = (bf16*)(ws + 9437184);
  bf16* h1    = (bf16*)(ws + 14155776);
  bf16* Qbuf  = (bf16*)(ws + 26738688);
  bf16* Kbuf  = (bf16*)(ws + 39321600);
  bf16* Vtbuf = (bf16*)(ws + 51904512);
  bf16* gb    = (bf16*)(ws + 14155776);  // reuse h1+Q+K+V region
  bf16* ctxb  = (bf16*)(ws + 64487424);
  bf16* h2    = (bf16*)(ws + 64487424);  // reuse ctx region
  float* outb = (float*)(ws + 77070336);
  float* y    = (float*)d_out;

  transpose_f32_bf16<<<dim3(24, 24), 256, 0, stream>>>(wq, wqkvt, 768, 768, 0.125f);
  transpose_f32_bf16<<<dim3(24, 24), 256, 0, stream>>>(wk, wqkvt + 768 * 768, 768, 768, 1.f);
  transpose_f32_bf16<<<dim3(24, 24), 256, 0, stream>>>(wv, wqkvt + 2 * 768 * 768, 768, 768, 1.f);
  transpose_f32_bf16<<<dim3(24, 24), 256, 0, stream>>>(wo, wot, 768, 768, 1.f);
  transpose_f32_bf16<<<dim3(96, 24), 256, 0, stream>>>(w1, w1t, 768, 3072, 1.f);
  transpose_f32_bf16<<<dim3(24, 96), 256, 0, stream>>>(w2, w2t, 3072, 768, 1.f);

  ln_bf16<<<ROWS, 256, 0, stream>>>(x, ln1g, ln1b, h1);

  // QKV: 256² thin-barrier, grid 32x9 = 288 (%8==0)
  gemm256_kernel<0><<<(ROWS / 256) * 9, 512, 0, stream>>>(
      h1, wqkvt, 768, 9, Qbuf, Kbuf, Vtbuf, bq, bk, bv);

  attn_kernel<<<CB * CH * 16, 256, 0, stream>>>(Qbuf, Kbuf, Vtbuf, ctxb);

  gemm_bf16_kernel<1><<<6 * (ROWS / 128), 256, 0, stream>>>(
      ctxb, wot, 768, 6, outb, bo, x);

  ln_bf16<<<ROWS, 256, 0, stream>>>(outb, ln2g, ln2b, h2);

  // MLP1: 256² thin-barrier, grid 32x12 = 384 (%8==0)
  gemm256_kernel<2><<<(ROWS / 256) * 12, 512, 0, stream>>>(
      h2, w1t, 768, 12, gb, nullptr, nullptr, b1, nullptr, nullptr);

  gemm_bf16_kernel<1><<<6 * (ROWS / 128), 256, 0, stream>>>(
      gb, w2t, 3072, 6, y, b2, outb);

  (void)in_sizes; (void)n_in; (void)out_size; (void)ws_size;
}